// Round 7
// baseline (201.124 us; speedup 1.0000x reference)
//
#include <hip/hip_runtime.h>
#include <hip/hip_bf16.h>

// B=2, T=2048, C=1024, H=16, D=64.  M = B*T = 4096.
// out = proj( attn( x@Wq^T, x@Wk^T, x@Wv^T ) ) @ Wp^T + bp   (softmax, NO causal mask)

typedef __bf16 bf16x8 __attribute__((ext_vector_type(8)));
typedef __bf16 bf16x4 __attribute__((ext_vector_type(4)));
typedef float  f32x4  __attribute__((ext_vector_type(4)));
typedef unsigned int uint2v __attribute__((ext_vector_type(2)));

#define QSCALE 0.18033688011112042f  /* 0.125 * log2(e): softmax in exp2 domain */

__device__ __forceinline__ void gload_lds16(const void* g, void* l) {
  __builtin_amdgcn_global_load_lds((const __attribute__((address_space(1))) void*)g,
                                   (__attribute__((address_space(3))) void*)l, 16, 0, 0);
}
__device__ __forceinline__ unsigned int lds_off(const void* p) {
  return (unsigned int)(uintptr_t)(__attribute__((address_space(3))) const char*)p;
}
// ds_read_b64_tr_b16: lane l receives bf16 elems (l&15) + j*16 + (l>>4)*64 of the 512B
// region at (base&~0x1ff)+IMM when per-lane addr = base + l*8.
template<int IMM>
__device__ __forceinline__ uint2v tr_b64(unsigned int addr) {
  uint2v r;
  asm volatile("ds_read_b64_tr_b16 %0, %1 offset:%2" : "=v"(r) : "v"(addr), "i"(IMM));
  return r;
}

// ---------------- fp32 -> bf16 conversion ----------------
__global__ __launch_bounds__(256) void cvt_bf16(
    const float* __restrict__ x,  const float* __restrict__ wq, const float* __restrict__ wk,
    const float* __restrict__ wv, const float* __restrict__ wp,
    __bf16* __restrict__ xb,  __bf16* __restrict__ wqb, __bf16* __restrict__ wkb,
    __bf16* __restrict__ wvb, __bf16* __restrict__ wpb) {
  long long i = ((long long)blockIdx.x * 256 + threadIdx.x) * 4;
  const float* src; __bf16* dst; long long off;
  if      (i < 4194304LL) { src = x;  dst = xb;  off = i; }
  else if (i < 5242880LL) { src = wq; dst = wqb; off = i - 4194304LL; }
  else if (i < 6291456LL) { src = wk; dst = wkb; off = i - 5242880LL; }
  else if (i < 7340032LL) { src = wv; dst = wvb; off = i - 6291456LL; }
  else                    { src = wp; dst = wpb; off = i - 7340032LL; }
  float4 v = *(const float4*)(src + off);
  bf16x4 o;
  o[0] = (__bf16)v.x; o[1] = (__bf16)v.y; o[2] = (__bf16)v.z; o[3] = (__bf16)v.w;
  *(bf16x4*)(dst + off) = o;
}

// ================= QKV: 256x256 tile, 8 waves, half-tile counted-vmcnt pipeline ========
// LDS: A,B each [2 bufs][2 halves][128 rows][64 k] bf16, rows linear 128B, source
// pre-swizzled so read byte = row*128 + (kbyte ^ ((row&7)<<4)) is conflict-free.
__device__ __forceinline__ void stage_half(const __bf16* src, int s0, int s1,
                                           char* d, int d0, int d1) {
  gload_lds16(src + s0, d + d0);
  gload_lds16(src + s1, d + d1);
}

template<int Q, int KK, bool LB>
__device__ __forceinline__ void qkv_phase(const char* pA, const char* pB,
    const unsigned int (&aoff)[2], bf16x8 (&bfr)[4], f32x4 (&acc)[8][4]) {
  bf16x8 af[4];
  #pragma unroll
  for (int i = 0; i < 4; ++i)
    af[i] = *(const bf16x8*)(pA + (Q * 4 + i) * 2048 + aoff[KK]);
  if constexpr (LB) {
    #pragma unroll
    for (int n = 0; n < 4; ++n)
      bfr[n] = *(const bf16x8*)(pB + n * 2048 + aoff[KK]);
  }
  __builtin_amdgcn_s_setprio(1);
  #pragma unroll
  for (int mi = 0; mi < 4; ++mi)
    #pragma unroll
    for (int n = 0; n < 4; ++n)
      acc[Q * 4 + mi][n] =
        __builtin_amdgcn_mfma_f32_16x16x32_bf16(af[mi], bfr[n], acc[Q * 4 + mi][n], 0, 0, 0);
  __builtin_amdgcn_s_setprio(0);
}

__global__ __launch_bounds__(512, 2) void gemm_qkv(
    const __bf16* __restrict__ Xb, const __bf16* __restrict__ Wcat,
    __bf16* __restrict__ QKVh) {
  __shared__ __align__(16) char smA[2][2][16384];
  __shared__ __align__(16) char smB[2][2][16384];
  const int tid = threadIdx.x, lane = tid & 63, wid = tid >> 6;
  const int lo = lane & 15, hi = lane >> 4;
  const int wr = wid >> 2, wc = wid & 3;
  const int tileM = blockIdx.x * 256, tileN = blockIdx.y * 256;

  // staging offsets: each half = 128 rows x 64 k = 1024 chunks of 16B; 2 chunks/thread
  int asrc[2][2], bsrc[2][2], sdst[2];
  #pragma unroll
  for (int r = 0; r < 2; ++r) {
    int ci = r * 512 + tid;
    int row = ci >> 3, c = ci & 7;
    int sc = (c ^ (row & 7)) * 8;
    sdst[r] = ci * 16;
    #pragma unroll
    for (int h = 0; h < 2; ++h) {
      asrc[h][r] = (tileM + h * 128 + row) * 1024 + sc;
      bsrc[h][r] = (tileN + h * 128 + row) * 1024 + sc;
    }
  }
  // fragment read offsets (row-local bits of XOR swizzle depend only on lo)
  unsigned int aoff[2];
  aoff[0] = lo * 128 + ((hi * 16) ^ ((lo & 7) << 4));
  aoff[1] = lo * 128 + ((64 + hi * 16) ^ ((lo & 7) << 4));

  f32x4 acc[8][4] = {};

  // prologue: stage K-tile 0 (A0,B0,B1,A1) into buf 0
  stage_half(Xb,   asrc[0][0], asrc[0][1], &smA[0][0][0], sdst[0], sdst[1]);
  stage_half(Wcat, bsrc[0][0], bsrc[0][1], &smB[0][0][0], sdst[0], sdst[1]);
  stage_half(Wcat, bsrc[1][0], bsrc[1][1], &smB[0][1][0], sdst[0], sdst[1]);
  stage_half(Xb,   asrc[1][0], asrc[1][1], &smA[0][1][0], sdst[0], sdst[1]);

  int buf = 0;
  #pragma unroll 1
  for (int t = 0; t < 16; ++t) {
    const char* pA = &smA[buf][wr][0];
    const char* pB = &smB[buf][wc >> 1][0] + (wc & 1) * 8192;
    char* nA0 = &smA[buf ^ 1][0][0];
    char* nA1 = &smA[buf ^ 1][1][0];
    char* nB0 = &smB[buf ^ 1][0][0];
    char* nB1 = &smB[buf ^ 1][1][0];
    const int ko = (t + 1) * 64;
    bf16x8 bfr[4];
    // P0: issue next A-half0, then counted wait (only the just-issued half may fly)
    if (t < 15) {
      stage_half(Xb, asrc[0][0] + ko, asrc[0][1] + ko, nA0, sdst[0], sdst[1]);
      asm volatile("s_waitcnt vmcnt(2)" ::: "memory");
    } else {
      asm volatile("s_waitcnt vmcnt(0)" ::: "memory");
    }
    __builtin_amdgcn_s_barrier();
    asm volatile("" ::: "memory");
    qkv_phase<0, 0, true >(pA, pB, aoff, bfr, acc);
    // P1: issue next B halves
    if (t < 15) {
      stage_half(Wcat, bsrc[0][0] + ko, bsrc[0][1] + ko, nB0, sdst[0], sdst[1]);
      stage_half(Wcat, bsrc[1][0] + ko, bsrc[1][1] + ko, nB1, sdst[0], sdst[1]);
    }
    qkv_phase<1, 0, false>(pA, pB, aoff, bfr, acc);
    // P2: issue next A-half1
    if (t < 15) {
      stage_half(Xb, asrc[1][0] + ko, asrc[1][1] + ko, nA1, sdst[0], sdst[1]);
    }
    qkv_phase<0, 1, true >(pA, pB, aoff, bfr, acc);
    // P3
    qkv_phase<1, 1, false>(pA, pB, aoff, bfr, acc);
    asm volatile("" ::: "memory");
    __builtin_amdgcn_s_barrier();
    asm volatile("" ::: "memory");
    buf ^= 1;
  }

  // epilogue: scatter into [3][B][H][T][D]; tiles never straddle the 1024 z-boundary
  const int z = tileN >> 10;
  const float scale = (z == 0) ? QSCALE : 1.0f;
  __bf16* dst = QKVh + (long long)z * 4194304;
  const int nbase = (tileN & 1023) + wc * 64;
  #pragma unroll
  for (int m = 0; m < 8; ++m) {
    #pragma unroll
    for (int n = 0; n < 4; ++n) {
      int ncol = nbase + n * 16 + lo;
      int h = ncol >> 6, d = ncol & 63;
      #pragma unroll
      for (int r = 0; r < 4; ++r) {
        int mg = tileM + wr * 128 + m * 16 + hi * 4 + r;
        int b = mg >> 11, tt = mg & 2047;
        dst[((b * 16 + h) * 2048 + tt) * 64 + d] = (__bf16)(acc[m][n][r] * scale);
      }
    }
  }
}

// ------- single-buffered GEMM core (round-4 proven) for the projection ----------------
template<int MFR>
__device__ __forceinline__ void gemm_core_sb(
    const __bf16* __restrict__ A, const __bf16* __restrict__ Bw,
    int tileM, int tileN, char* smA, char* smB, f32x4 (&acc)[MFR][4]) {
  const int tid = threadIdx.x;
  const int lane = tid & 63;
  const int wid = tid >> 6;
  const int wr = wid >> 1, wc = wid & 1;
  #pragma unroll 1
  for (int k0 = 0; k0 < 1024; k0 += 64) {
    __syncthreads();
    #pragma unroll
    for (int r = 0; r < MFR; ++r) {
      int ci = tid + 256 * r;
      int row = ci >> 3, c = ci & 7;
      int sc = (c ^ (row & 7)) * 8;
      gload_lds16(A + (long long)(tileM + row) * 1024 + k0 + sc, smA + ci * 16);
    }
    #pragma unroll
    for (int r = 0; r < 4; ++r) {
      int ci = tid + 256 * r;
      int row = ci >> 3, c = ci & 7;
      int sc = (c ^ (row & 7)) * 8;
      gload_lds16(Bw + (long long)(tileN + row) * 1024 + k0 + sc, smB + ci * 16);
    }
    __syncthreads();
    #pragma unroll
    for (int kk = 0; kk < 2; ++kk) {
      bf16x8 af[MFR], bfr[4];
      #pragma unroll
      for (int i = 0; i < MFR; ++i) {
        int mrow = wr * (MFR * 16) + i * 16 + (lane & 15);
        af[i] = *(const bf16x8*)(smA + mrow * 128 +
                  ((kk * 64 + (lane >> 4) * 16) ^ ((mrow & 7) << 4)));
      }
      #pragma unroll
      for (int i = 0; i < 4; ++i) {
        int nrow = wc * 64 + i * 16 + (lane & 15);
        bfr[i] = *(const bf16x8*)(smB + nrow * 128 +
                  ((kk * 64 + (lane >> 4) * 16) ^ ((nrow & 7) << 4)));
      }
      __builtin_amdgcn_s_setprio(1);
      #pragma unroll
      for (int mi = 0; mi < MFR; ++mi)
        #pragma unroll
        for (int ni = 0; ni < 4; ++ni)
          acc[mi][ni] = __builtin_amdgcn_mfma_f32_16x16x32_bf16(af[mi], bfr[ni], acc[mi][ni], 0, 0, 0);
      __builtin_amdgcn_s_setprio(0);
    }
  }
}

// ---------------- output projection + bias, fp32 out (64x128 tiles) ----------------
__global__ __launch_bounds__(256) void gemm_proj(
    const __bf16* __restrict__ Yb, const __bf16* __restrict__ Wpb,
    const float* __restrict__ bias, float* __restrict__ out) {
  __shared__ __align__(16) char smA[8192];
  __shared__ __align__(16) char smB[16384];
  const int tileM = blockIdx.x * 64, tileN = blockIdx.y * 128;
  f32x4 acc[2][4] = {};
  gemm_core_sb<2>(Yb, Wpb, tileM, tileN, smA, smB, acc);
  const int lane = threadIdx.x & 63, wid = threadIdx.x >> 6;
  const int wr = wid >> 1, wc = wid & 1;
  #pragma unroll
  for (int mi = 0; mi < 2; ++mi) {
    #pragma unroll
    for (int ni = 0; ni < 4; ++ni) {
      int n = tileN + wc * 64 + ni * 16 + (lane & 15);
      float bv = bias[n];
      #pragma unroll
      for (int r = 0; r < 4; ++r) {
        int m = tileM + wr * 32 + mi * 16 + (lane >> 4) * 4 + r;
        out[(long long)m * 1024 + n] = acc[mi][ni][r] + bv;
      }
    }
  }
}

// ---------------- flash attention, static max, KV-split x2, 8 waves, 2-phase ----------
template<int KS>
__device__ __forceinline__ void pv_half(unsigned int trP, unsigned int trV,
                                        f32x4 Oa[2][4], f32x4 Osum[2], bf16x8 ones) {
  uint2v pl[2], ph[2];
  pl[0] = tr_b64<0 * 2048 + KS * 1024      >(trP);
  ph[0] = tr_b64<0 * 2048 + KS * 1024 + 512>(trP);
  pl[1] = tr_b64<1 * 2048 + KS * 1024      >(trP);
  ph[1] = tr_b64<1 * 2048 + KS * 1024 + 512>(trP);
  uint2v t0[4], t1[4];
  t0[0] = tr_b64<KS * 1024 + 0 * 2048>(trV);  t1[0] = tr_b64<KS * 1024 + 0 * 2048 + 512>(trV);
  t0[1] = tr_b64<KS * 1024 + 1 * 2048>(trV);  t1[1] = tr_b64<KS * 1024 + 1 * 2048 + 512>(trV);
  t0[2] = tr_b64<KS * 1024 + 2 * 2048>(trV);  t1[2] = tr_b64<KS * 1024 + 2 * 2048 + 512>(trV);
  t0[3] = tr_b64<KS * 1024 + 3 * 2048>(trV);  t1[3] = tr_b64<KS * 1024 + 3 * 2048 + 512>(trV);
  asm volatile("s_waitcnt lgkmcnt(0)");
  __builtin_amdgcn_sched_barrier(0);
  __builtin_amdgcn_s_setprio(1);
  bf16x8 pa[2];
  #pragma unroll
  for (int mi = 0; mi < 2; ++mi) {
    uint4 u; u.x = pl[mi][0]; u.y = pl[mi][1]; u.z = ph[mi][0]; u.w = ph[mi][1];
    pa[mi] = __builtin_bit_cast(bf16x8, u);
    Osum[mi] = __builtin_amdgcn_mfma_f32_16x16x32_bf16(pa[mi], ones, Osum[mi], 0, 0, 0);
  }
  #pragma unroll
  for (int nd = 0; nd < 4; ++nd) {
    uint4 u; u.x = t0[nd][0]; u.y = t0[nd][1]; u.z = t1[nd][0]; u.w = t1[nd][1];
    bf16x8 vf = __builtin_bit_cast(bf16x8, u);
    #pragma unroll
    for (int mi = 0; mi < 2; ++mi)
      Oa[mi][nd] = __builtin_amdgcn_mfma_f32_16x16x32_bf16(pa[mi], vf, Oa[mi][nd], 0, 0, 0);
  }
  __builtin_amdgcn_s_setprio(0);
}

__global__ __launch_bounds__(512, 4) void attn(
    const __bf16* __restrict__ Qh, const __bf16* __restrict__ Kh,
    const __bf16* __restrict__ Vh, float* __restrict__ Opart,
    float* __restrict__ lpart) {
  __shared__ __align__(16) char Ksm[2][8192];   // [64 keys][64 d] swizzled rows, dbuf
  __shared__ __align__(16) char Vsm[2][8192];   // tr-read layout, dbuf
  __shared__ __align__(16) char Psm[32768];     // per-wave P^T, tr-read layout (8 x 4KB)
  const int tid = threadIdx.x, lane = tid & 63, wid = tid >> 6;
  const int lo = lane & 15, hi = lane >> 4;
  const int bh = blockIdx.x;                 // 0..31 = b*16+h
  const int qb = blockIdx.y;                 // 0..7
  const int split = blockIdx.z;              // 0..1 (KV halves)
  const int base = bh * (2048 * 64);
  const int qrow0 = qb * 256 + wid * 32;
  const int key0 = split * 1024;

  bf16x8 qf[2][2];
  #pragma unroll
  for (int mi = 0; mi < 2; ++mi)
    #pragma unroll
    for (int kk = 0; kk < 2; ++kk)
      qf[mi][kk] = *(const bf16x8*)(Qh + base + (qrow0 + mi * 16 + lo) * 64
                                    + kk * 32 + hi * 8);

  bf16x8 ones;
  #pragma unroll
  for (int j = 0; j < 8; ++j) ones[j] = (__bf16)1.0f;

  f32x4 Oa[2][4] = {};
  f32x4 Osum[2] = {};
  const unsigned int trP = lds_off(Psm) + wid * 4096 + lane * 8;

  unsigned int koff[4];
  #pragma unroll
  for (int ni = 0; ni < 4; ++ni) {
    int row = ni * 16 + lo;
    koff[ni] = row * 128 + ((hi * 16) ^ ((row & 7) << 4));
  }
  unsigned int paddr[2][4];
  #pragma unroll
  for (int mi = 0; mi < 2; ++mi)
    #pragma unroll
    for (int ni = 0; ni < 4; ++ni) {
      int kq = ni * 16 + lo;
      paddr[mi][ni] = wid * 4096 + mi * 2048 + (kq >> 5) * 1024 + ((kq >> 2) & 1) * 512 +
                      ((kq >> 3) & 3) * 128 + (kq & 3) * 32 + hi * 8;
    }

  int krow = tid >> 3, kc = tid & 7;
  int ksrc = base + (key0 + krow) * 64 + (kc ^ (krow & 7)) * 8;
  int kdst = tid * 16;
  int vcc = tid >> 6, vks = vcc & 1, vd4 = vcc >> 1;
  int vkey = vks * 32 + ((lane >> 3) & 3) * 8 + ((lane >> 5) & 1) * 4 + ((lane >> 1) & 3);
  int vsrc = base + (key0 + vkey) * 64 + vd4 * 16 + (lane & 1) * 8;
  int vdst = vks * 1024 + vd4 * 2048 + lane * 16;

  gload_lds16(Kh + ksrc, &Ksm[0][0] + kdst);
  gload_lds16(Vh + vsrc, &Vsm[0][0] + vdst);
  __syncthreads();
  int buf = 0;

  #pragma unroll 1
  for (int kt = 0; kt < 16; ++kt) {
    if (kt < 15) {
      gload_lds16(Kh + ksrc + (kt + 1) * 4096, &Ksm[buf ^ 1][0] + kdst);
      gload_lds16(Vh + vsrc + (kt + 1) * 4096, &Vsm[buf ^ 1][0] + vdst);
    }
    __builtin_amdgcn_sched_barrier(0);

    const char* Kb = &Ksm[buf][0];
    const unsigned int trV = lds_off(Vsm) + buf * 8192 + lane * 8;

    f32x4 S[2][4] = {};
    #pragma unroll
    for (int kk = 0; kk < 2; ++kk) {
      bf16x8 kf[4];
      #pragma unroll
      for (int ni = 0; ni < 4; ++ni)
        kf[ni] = *(const bf16x8*)(Kb + (koff[ni] ^ (kk * 64)));
      __builtin_amdgcn_s_setprio(1);
      #pragma unroll
      for (int mi = 0; mi < 2; ++mi)
        #pragma unroll
        for (int ni = 0; ni < 4; ++ni)
          S[mi][ni] = __builtin_amdgcn_mfma_f32_16x16x32_bf16(qf[mi][kk], kf[ni], S[mi][ni], 0, 0, 0);
      __builtin_amdgcn_s_setprio(0);
    }

    #pragma unroll
    for (int mi = 0; mi < 2; ++mi) {
      #pragma unroll
      for (int ni = 0; ni < 4; ++ni) {
        bf16x4 pb;
        #pragma unroll
        for (int r = 0; r < 4; ++r) pb[r] = (__bf16)exp2f(S[mi][ni][r]);
        *(bf16x4*)(&Psm[0] + paddr[mi][ni]) = pb;
      }
    }

    pv_half<0>(trP, trV, Oa, Osum, ones);
    pv_half<1>(trP, trV, Oa, Osum, ones);

    __syncthreads();
    buf ^= 1;
  }

  float* Op = Opart + (long long)(split * 32 + bh) * 2048 * 64;
  float* lp = lpart + (split * 32 + bh) * 2048;
  #pragma unroll
  for (int mi = 0; mi < 2; ++mi) {
    #pragma unroll
    for (int r = 0; r < 4; ++r) {
      int t = qrow0 + mi * 16 + hi * 4 + r;
      if (lo == 0) lp[t] = Osum[mi][r];
      #pragma unroll
      for (int nd = 0; nd < 4; ++nd)
        Op[(long long)t * 64 + nd * 16 + lo] = Oa[mi][nd][r];
    }
  }
}

// ---------------- combine partials -> Yb [B][T][C] bf16 ----------------
__global__ __launch_bounds__(256) void attn_combine(
    const float* __restrict__ Opart, const float* __restrict__ lpart,
    __bf16* __restrict__ Yb) {
  int i = blockIdx.x * 256 + threadIdx.x;    // 1M threads
  int row = i >> 4;                          // bh*2048 + t
  int d0 = (i & 15) * 4;
  float4 o0 = *(const float4*)(Opart + (long long)row * 64 + d0);
  float4 o1 = *(const float4*)(Opart + 4194304LL + (long long)row * 64 + d0);
  float inv = 1.0f / (lpart[row] + lpart[65536 + row]);
  int bh = row >> 11, t = row & 2047;
  int b = bh >> 4, h = bh & 15;
  bf16x4 o;
  o[0] = (__bf16)((o0.x + o1.x) * inv); o[1] = (__bf16)((o0.y + o1.y) * inv);
  o[2] = (__bf16)((o0.z + o1.z) * inv); o[3] = (__bf16)((o0.w + o1.w) * inv);
  *(bf16x4*)(Yb + ((long long)(b * 2048 + t)) * 1024 + h * 64 + d0) = o;
}

// ---------------- launch ----------------
extern "C" void kernel_launch(void* const* d_in, const int* in_sizes, int n_in,
                              void* d_out, int out_size, void* d_ws, size_t ws_size,
                              hipStream_t stream) {
  const float* x  = (const float*)d_in[0];
  const float* Wk = (const float*)d_in[1];
  const float* Wq = (const float*)d_in[2];
  const float* Wv = (const float*)d_in[3];
  const float* Wp = (const float*)d_in[4];
  const float* bp = (const float*)d_in[5];
  float* out = (float*)d_out;

  char* ws = (char*)d_ws;
  __bf16* Xb  = (__bf16*)ws;                 // 4096*1024
  __bf16* Wqb = Xb  + 4194304;               // 1024*1024 each; Wq,Wk,Wv contiguous
  __bf16* Wkb = Wqb + 1048576;
  __bf16* Wvb = Wkb + 1048576;
  __bf16* Wpb = Wvb + 1048576;
  __bf16* Qh  = Wpb + 1048576;               // [B][H][T][D]; Q,K,V contiguous
  __bf16* Kh  = Qh  + 4194304;
  __bf16* Vh  = Kh  + 4194304;
  __bf16* Yb  = Vh  + 4194304;               // [B][T][C]
  float*  Opart = (float*)(Yb + 4194304);    // [2][32][2048][64] f32
  float*  lpart = Opart + 8388608;           // [2][32][2048]    f32

  cvt_bf16<<<8192, 256, 0, stream>>>(x, Wq, Wk, Wv, Wp, Xb, Wqb, Wkb, Wvb, Wpb);
  gemm_qkv<<<dim3(16, 12), 512, 0, stream>>>(Xb, Wqb, Qh);
  attn<<<dim3(32, 8, 2), 512, 0, stream>>>(Qh, Kh, Vh, Opart, lpart);
  attn_combine<<<4096, 256, 0, stream>>>(Opart, lpart, Yb);
  gemm_proj<<<dim3(64, 8), 256, 0, stream>>>(Yb, Wpb, bp, out);
}

// Round 9
// 190.602 us; speedup vs baseline: 1.0552x; 1.0552x over previous
//
#include <hip/hip_runtime.h>
#include <hip/hip_bf16.h>

// B=2, T=2048, C=1024, H=16, D=64.  M = B*T = 4096.
// out = proj( attn( x@Wq^T, x@Wk^T, x@Wv^T ) ) @ Wp^T + bp   (softmax, NO causal mask)

typedef __bf16 bf16x8 __attribute__((ext_vector_type(8)));
typedef __bf16 bf16x4 __attribute__((ext_vector_type(4)));
typedef float  f32x4  __attribute__((ext_vector_type(4)));
typedef unsigned int uint2v __attribute__((ext_vector_type(2)));

#define QSCALE 0.18033688011112042f  /* 0.125 * log2(e): softmax in exp2 domain */

__device__ __forceinline__ void gload_lds16(const void* g, void* l) {
  __builtin_amdgcn_global_load_lds((const __attribute__((address_space(1))) void*)g,
                                   (__attribute__((address_space(3))) void*)l, 16, 0, 0);
}
__device__ __forceinline__ unsigned int lds_off(const void* p) {
  return (unsigned int)(uintptr_t)(__attribute__((address_space(3))) const char*)p;
}
// ds_read_b64_tr_b16: lane l receives bf16 elems (l&15) + j*16 + (l>>4)*64 of the 512B
// region at (base&~0x1ff)+IMM when per-lane addr = base + l*8.
template<int IMM>
__device__ __forceinline__ uint2v tr_b64(unsigned int addr) {
  uint2v r;
  asm volatile("ds_read_b64_tr_b16 %0, %1 offset:%2" : "=v"(r) : "v"(addr), "i"(IMM));
  return r;
}
// packed fp32->bf16 (RNE), src0 -> low half
__device__ __forceinline__ unsigned int cvtpk_bf16(float a, float b) {
  unsigned int r;
  asm("v_cvt_pk_bf16_f32 %0, %1, %2" : "=v"(r) : "v"(a), "v"(b));
  return r;
}

// ---------------- fp32 -> bf16 conversion ----------------
__global__ __launch_bounds__(256) void cvt_bf16(
    const float* __restrict__ x,  const float* __restrict__ wq, const float* __restrict__ wk,
    const float* __restrict__ wv, const float* __restrict__ wp,
    __bf16* __restrict__ xb,  __bf16* __restrict__ wqb, __bf16* __restrict__ wkb,
    __bf16* __restrict__ wvb, __bf16* __restrict__ wpb) {
  long long i = ((long long)blockIdx.x * 256 + threadIdx.x) * 4;
  const float* src; __bf16* dst; long long off;
  if      (i < 4194304LL) { src = x;  dst = xb;  off = i; }
  else if (i < 5242880LL) { src = wq; dst = wqb; off = i - 4194304LL; }
  else if (i < 6291456LL) { src = wk; dst = wkb; off = i - 5242880LL; }
  else if (i < 7340032LL) { src = wv; dst = wvb; off = i - 6291456LL; }
  else                    { src = wp; dst = wpb; off = i - 7340032LL; }
  float4 v = *(const float4*)(src + off);
  bf16x4 o;
  o[0] = (__bf16)v.x; o[1] = (__bf16)v.y; o[2] = (__bf16)v.z; o[3] = (__bf16)v.w;
  *(bf16x4*)(dst + off) = o;
}

// ------- single-buffered GEMM core (round-4 proven): C[(MFR*32) x 128] ----------------
// LDS rows linear 128B, source pre-swizzled; reads XOR-swizzled -> conflict-free.
template<int MFR>
__device__ __forceinline__ void gemm_core_sb(
    const __bf16* __restrict__ A, const __bf16* __restrict__ Bw,
    int tileM, int tileN, char* smA, char* smB, f32x4 (&acc)[MFR][4]) {
  const int tid = threadIdx.x;
  const int lane = tid & 63;
  const int wid = tid >> 6;
  const int wr = wid >> 1, wc = wid & 1;
  #pragma unroll 1
  for (int k0 = 0; k0 < 1024; k0 += 64) {
    __syncthreads();
    #pragma unroll
    for (int r = 0; r < MFR; ++r) {
      int ci = tid + 256 * r;
      int row = ci >> 3, c = ci & 7;
      int sc = (c ^ (row & 7)) * 8;
      gload_lds16(A + (long long)(tileM + row) * 1024 + k0 + sc, smA + ci * 16);
    }
    #pragma unroll
    for (int r = 0; r < 4; ++r) {
      int ci = tid + 256 * r;
      int row = ci >> 3, c = ci & 7;
      int sc = (c ^ (row & 7)) * 8;
      gload_lds16(Bw + (long long)(tileN + row) * 1024 + k0 + sc, smB + ci * 16);
    }
    __syncthreads();
    #pragma unroll
    for (int kk = 0; kk < 2; ++kk) {
      bf16x8 af[MFR], bfr[4];
      #pragma unroll
      for (int i = 0; i < MFR; ++i) {
        int mrow = wr * (MFR * 16) + i * 16 + (lane & 15);
        af[i] = *(const bf16x8*)(smA + mrow * 128 +
                  ((kk * 64 + (lane >> 4) * 16) ^ ((mrow & 7) << 4)));
      }
      #pragma unroll
      for (int i = 0; i < 4; ++i) {
        int nrow = wc * 64 + i * 16 + (lane & 15);
        bfr[i] = *(const bf16x8*)(smB + nrow * 128 +
                  ((kk * 64 + (lane >> 4) * 16) ^ ((nrow & 7) << 4)));
      }
      __builtin_amdgcn_s_setprio(1);
      #pragma unroll
      for (int mi = 0; mi < MFR; ++mi)
        #pragma unroll
        for (int ni = 0; ni < 4; ++ni)
          acc[mi][ni] = __builtin_amdgcn_mfma_f32_16x16x32_bf16(af[mi], bfr[ni], acc[mi][ni], 0, 0, 0);
      __builtin_amdgcn_s_setprio(0);
    }
  }
}

// ---------------- QKV projection: writes [B][H][T][D] bf16, Q pre-scaled ----------------
__global__ __launch_bounds__(256) void gemm_qkv(
    const __bf16* __restrict__ Xb, const __bf16* __restrict__ Wqb,
    const __bf16* __restrict__ Wkb, const __bf16* __restrict__ Wvb,
    __bf16* __restrict__ Qh, __bf16* __restrict__ Kh, __bf16* __restrict__ Vh) {
  __shared__ __align__(16) char smA[16384];
  __shared__ __align__(16) char smB[16384];
  const int z = blockIdx.z;
  const __bf16* W = (z == 0) ? Wqb : (z == 1) ? Wkb : Wvb;
  __bf16* dst     = (z == 0) ? Qh  : (z == 1) ? Kh  : Vh;
  const float scale = (z == 0) ? QSCALE : 1.0f;
  const int tileM = blockIdx.x * 128, tileN = blockIdx.y * 128;
  f32x4 acc[4][4] = {};
  gemm_core_sb<4>(Xb, W, tileM, tileN, smA, smB, acc);
  const int lane = threadIdx.x & 63, wid = threadIdx.x >> 6;
  const int wr = wid >> 1, wc = wid & 1;
  #pragma unroll
  for (int mi = 0; mi < 4; ++mi) {
    #pragma unroll
    for (int ni = 0; ni < 4; ++ni) {
      int n = tileN + wc * 64 + ni * 16 + (lane & 15);
      int h = n >> 6, d = n & 63;
      #pragma unroll
      for (int r = 0; r < 4; ++r) {
        int m = tileM + wr * 64 + mi * 16 + (lane >> 4) * 4 + r;
        int b = m >> 11, t = m & 2047;
        dst[((b * 16 + h) * 2048 + t) * 64 + d] = (__bf16)(acc[mi][ni][r] * scale);
      }
    }
  }
}

// -------- output projection + bias, fused combine (reads Opart/lpart directly) --------
// A-staging is reg-staged: y[t][c] = (O0[t][c]+O1[t][c]) / (l0[t]+l1[t]), cast bf16,
// written into the same swizzled LDS image the SB core expects.  64x128 tiles.
// Opart: [2 splits][32 bh][2048 t][64 d] f32 (split stride 4194304 ELEMENTS).
__global__ __launch_bounds__(256) void gemm_proj(
    const float* __restrict__ Opart, const float* __restrict__ lpart,
    const __bf16* __restrict__ Wpb, const float* __restrict__ bias,
    float* __restrict__ out) {
  __shared__ __align__(16) char smA[8192];
  __shared__ __align__(16) char smB[16384];
  const int tid = threadIdx.x, lane = tid & 63, wid = tid >> 6;
  const int wr = wid >> 1, wc = wid & 1;
  const int tileM = blockIdx.x * 64, tileN = blockIdx.y * 128;
  f32x4 acc[2][4] = {};

  // A-chunk precompute: chunk ci covers row=ci>>3 (64 rows), d0=(c^(row&7))*8
  // K-step ks = head h; global column = ks*64 + d0.
  int aoff0[2], al0[2], adst[2];
  #pragma unroll
  for (int r = 0; r < 2; ++r) {
    int ci = tid + 256 * r;
    int row = ci >> 3, c = ci & 7;
    int d0 = (c ^ (row & 7)) * 8;
    int m = tileM + row;
    int b = m >> 11, t = m & 2047;
    aoff0[r] = b * 2097152 + t * 64 + d0;   // + ks*131072 per K-step; Opart split 0
    al0[r]   = b * 32768 + t;               // + ks*2048;  lpart split 0
    adst[r]  = ci * 16;
  }
  long long bsrc[4]; int bdst[4];
  #pragma unroll
  for (int r = 0; r < 4; ++r) {
    int ci = tid + 256 * r;
    int row = ci >> 3, c = ci & 7;
    bsrc[r] = (long long)(tileN + row) * 1024 + (c ^ (row & 7)) * 8;
    bdst[r] = ci * 16;
  }

  #pragma unroll 1
  for (int ks = 0; ks < 16; ++ks) {
    __syncthreads();
    // B: async global->LDS
    #pragma unroll
    for (int r = 0; r < 4; ++r)
      gload_lds16(Wpb + bsrc[r] + ks * 64, smB + bdst[r]);
    // A: combine + normalize + cvt -> ds_write_b128
    #pragma unroll
    for (int r = 0; r < 2; ++r) {
      const float* p0 = Opart + aoff0[r] + ks * 131072;
      const float* p1 = p0 + 4194304;       // split stride in ELEMENTS (bug fixed)
      float4 x0 = *(const float4*)p0;
      float4 x1 = *(const float4*)(p0 + 4);
      float4 y0 = *(const float4*)p1;
      float4 y1 = *(const float4*)(p1 + 4);
      int li = al0[r] + ks * 2048;
      float inv = 1.0f / (lpart[li] + lpart[65536 + li]);
      uint4 w;
      w.x = cvtpk_bf16((x0.x + y0.x) * inv, (x0.y + y0.y) * inv);
      w.y = cvtpk_bf16((x0.z + y0.z) * inv, (x0.w + y0.w) * inv);
      w.z = cvtpk_bf16((x1.x + y1.x) * inv, (x1.y + y1.y) * inv);
      w.w = cvtpk_bf16((x1.z + y1.z) * inv, (x1.w + y1.w) * inv);
      *(uint4*)(smA + adst[r]) = w;
    }
    __syncthreads();
    #pragma unroll
    for (int kk = 0; kk < 2; ++kk) {
      bf16x8 af[2], bfr[4];
      #pragma unroll
      for (int i = 0; i < 2; ++i) {
        int mrow = wr * 32 + i * 16 + (lane & 15);
        af[i] = *(const bf16x8*)(smA + mrow * 128 +
                  ((kk * 64 + (lane >> 4) * 16) ^ ((mrow & 7) << 4)));
      }
      #pragma unroll
      for (int i = 0; i < 4; ++i) {
        int nrow = wc * 64 + i * 16 + (lane & 15);
        bfr[i] = *(const bf16x8*)(smB + nrow * 128 +
                  ((kk * 64 + (lane >> 4) * 16) ^ ((nrow & 7) << 4)));
      }
      __builtin_amdgcn_s_setprio(1);
      #pragma unroll
      for (int mi = 0; mi < 2; ++mi)
        #pragma unroll
        for (int ni = 0; ni < 4; ++ni)
          acc[mi][ni] = __builtin_amdgcn_mfma_f32_16x16x32_bf16(af[mi], bfr[ni], acc[mi][ni], 0, 0, 0);
      __builtin_amdgcn_s_setprio(0);
    }
  }

  #pragma unroll
  for (int mi = 0; mi < 2; ++mi) {
    #pragma unroll
    for (int ni = 0; ni < 4; ++ni) {
      int n = tileN + wc * 64 + ni * 16 + (lane & 15);
      float bv = bias[n];
      #pragma unroll
      for (int r = 0; r < 4; ++r) {
        int m = tileM + wr * 32 + mi * 16 + (lane >> 4) * 4 + r;
        out[(long long)m * 1024 + n] = acc[mi][ni][r] + bv;
      }
    }
  }
}

// ---------------- flash attention, static max, KV-split x2, 8 waves, 2-phase ----------
template<int KS>
__device__ __forceinline__ void pv_half(unsigned int trP, unsigned int trV,
                                        f32x4 Oa[2][4], f32x4 Osum[2], bf16x8 ones) {
  uint2v pl[2], ph[2];
  pl[0] = tr_b64<0 * 2048 + KS * 1024      >(trP);
  ph[0] = tr_b64<0 * 2048 + KS * 1024 + 512>(trP);
  pl[1] = tr_b64<1 * 2048 + KS * 1024      >(trP);
  ph[1] = tr_b64<1 * 2048 + KS * 1024 + 512>(trP);
  uint2v t0[4], t1[4];
  t0[0] = tr_b64<KS * 1024 + 0 * 2048>(trV);  t1[0] = tr_b64<KS * 1024 + 0 * 2048 + 512>(trV);
  t0[1] = tr_b64<KS * 1024 + 1 * 2048>(trV);  t1[1] = tr_b64<KS * 1024 + 1 * 2048 + 512>(trV);
  t0[2] = tr_b64<KS * 1024 + 2 * 2048>(trV);  t1[2] = tr_b64<KS * 1024 + 2 * 2048 + 512>(trV);
  t0[3] = tr_b64<KS * 1024 + 3 * 2048>(trV);  t1[3] = tr_b64<KS * 1024 + 3 * 2048 + 512>(trV);
  asm volatile("s_waitcnt lgkmcnt(0)");
  __builtin_amdgcn_sched_barrier(0);
  __builtin_amdgcn_s_setprio(1);
  bf16x8 pa[2];
  #pragma unroll
  for (int mi = 0; mi < 2; ++mi) {
    uint4 u; u.x = pl[mi][0]; u.y = pl[mi][1]; u.z = ph[mi][0]; u.w = ph[mi][1];
    pa[mi] = __builtin_bit_cast(bf16x8, u);
    Osum[mi] = __builtin_amdgcn_mfma_f32_16x16x32_bf16(pa[mi], ones, Osum[mi], 0, 0, 0);
  }
  #pragma unroll
  for (int nd = 0; nd < 4; ++nd) {
    uint4 u; u.x = t0[nd][0]; u.y = t0[nd][1]; u.z = t1[nd][0]; u.w = t1[nd][1];
    bf16x8 vf = __builtin_bit_cast(bf16x8, u);
    #pragma unroll
    for (int mi = 0; mi < 2; ++mi)
      Oa[mi][nd] = __builtin_amdgcn_mfma_f32_16x16x32_bf16(pa[mi], vf, Oa[mi][nd], 0, 0, 0);
  }
  __builtin_amdgcn_s_setprio(0);
}

__global__ __launch_bounds__(512, 4) void attn(
    const __bf16* __restrict__ Qh, const __bf16* __restrict__ Kh,
    const __bf16* __restrict__ Vh, float* __restrict__ Opart,
    float* __restrict__ lpart) {
  __shared__ __align__(16) char Ksm[2][8192];   // [64 keys][64 d] swizzled rows, dbuf
  __shared__ __align__(16) char Vsm[2][8192];   // tr-read layout, dbuf
  __shared__ __align__(16) char Psm[32768];     // per-wave P^T, tr-read layout (8 x 4KB)
  const int tid = threadIdx.x, lane = tid & 63, wid = tid >> 6;
  const int lo = lane & 15, hi = lane >> 4;
  const int bh = blockIdx.x;                 // 0..31 = b*16+h
  const int qb = blockIdx.y;                 // 0..7
  const int split = blockIdx.z;              // 0..1 (KV halves)
  const int base = bh * (2048 * 64);
  const int qrow0 = qb * 256 + wid * 32;
  const int key0 = split * 1024;

  bf16x8 qf[2][2];
  #pragma unroll
  for (int mi = 0; mi < 2; ++mi)
    #pragma unroll
    for (int kk = 0; kk < 2; ++kk)
      qf[mi][kk] = *(const bf16x8*)(Qh + base + (qrow0 + mi * 16 + lo) * 64
                                    + kk * 32 + hi * 8);

  bf16x8 ones;
  #pragma unroll
  for (int j = 0; j < 8; ++j) ones[j] = (__bf16)1.0f;

  f32x4 Oa[2][4] = {};
  f32x4 Osum[2] = {};
  const unsigned int trP = lds_off(Psm) + wid * 4096 + lane * 8;

  unsigned int koff[4];
  #pragma unroll
  for (int ni = 0; ni < 4; ++ni) {
    int row = ni * 16 + lo;
    koff[ni] = row * 128 + ((hi * 16) ^ ((row & 7) << 4));
  }
  unsigned int paddr[2][4];
  #pragma unroll
  for (int mi = 0; mi < 2; ++mi)
    #pragma unroll
    for (int ni = 0; ni < 4; ++ni) {
      int kq = ni * 16 + lo;
      paddr[mi][ni] = wid * 4096 + mi * 2048 + (kq >> 5) * 1024 + ((kq >> 2) & 1) * 512 +
                      ((kq >> 3) & 3) * 128 + (kq & 3) * 32 + hi * 8;
    }

  int krow = tid >> 3, kc = tid & 7;
  int ksrc = base + (key0 + krow) * 64 + (kc ^ (krow & 7)) * 8;
  int kdst = tid * 16;
  int vcc = tid >> 6, vks = vcc & 1, vd4 = vcc >> 1;
  int vkey = vks * 32 + ((lane >> 3) & 3) * 8 + ((lane >> 5) & 1) * 4 + ((lane >> 1) & 3);
  int vsrc = base + (key0 + vkey) * 64 + vd4 * 16 + (lane & 1) * 8;
  int vdst = vks * 1024 + vd4 * 2048 + lane * 16;

  gload_lds16(Kh + ksrc, &Ksm[0][0] + kdst);
  gload_lds16(Vh + vsrc, &Vsm[0][0] + vdst);
  __syncthreads();
  int buf = 0;

  #pragma unroll 1
  for (int kt = 0; kt < 16; ++kt) {
    if (kt < 15) {
      gload_lds16(Kh + ksrc + (kt + 1) * 4096, &Ksm[buf ^ 1][0] + kdst);
      gload_lds16(Vh + vsrc + (kt + 1) * 4096, &Vsm[buf ^ 1][0] + vdst);
    }
    __builtin_amdgcn_sched_barrier(0);

    const char* Kb = &Ksm[buf][0];
    const unsigned int trV = lds_off(Vsm) + buf * 8192 + lane * 8;

    f32x4 S[2][4] = {};
    #pragma unroll
    for (int kk = 0; kk < 2; ++kk) {
      bf16x8 kf[4];
      #pragma unroll
      for (int ni = 0; ni < 4; ++ni)
        kf[ni] = *(const bf16x8*)(Kb + (koff[ni] ^ (kk * 64)));
      __builtin_amdgcn_s_setprio(1);
      #pragma unroll
      for (int mi = 0; mi < 2; ++mi)
        #pragma unroll
        for (int ni = 0; ni < 4; ++ni)
          S[mi][ni] = __builtin_amdgcn_mfma_f32_16x16x32_bf16(qf[mi][kk], kf[ni], S[mi][ni], 0, 0, 0);
      __builtin_amdgcn_s_setprio(0);
    }

    // static-max softmax: p = exp2(S); packed cvt_pk -> one b64 write per (mi,ni)
    #pragma unroll
    for (int mi = 0; mi < 2; ++mi) {
      #pragma unroll
      for (int ni = 0; ni < 4; ++ni) {
        float e0 = exp2f(S[mi][ni][0]);
        float e1 = exp2f(S[mi][ni][1]);
        float e2 = exp2f(S[mi][ni][2]);
        float e3 = exp2f(S[mi][ni][3]);
        uint2v w;
        w[0] = cvtpk_bf16(e0, e1);
        w[1] = cvtpk_bf16(e2, e3);
        *(uint2v*)(&Psm[0] + paddr[mi][ni]) = w;
      }
    }

    pv_half<0>(trP, trV, Oa, Osum, ones);
    pv_half<1>(trP, trV, Oa, Osum, ones);

    __syncthreads();
    buf ^= 1;
  }

  float* Op = Opart + (long long)(split * 32 + bh) * 2048 * 64;
  float* lp = lpart + (split * 32 + bh) * 2048;
  #pragma unroll
  for (int mi = 0; mi < 2; ++mi) {
    #pragma unroll
    for (int r = 0; r < 4; ++r) {
      int t = qrow0 + mi * 16 + hi * 4 + r;
      if (lo == 0) lp[t] = Osum[mi][r];
      #pragma unroll
      for (int nd = 0; nd < 4; ++nd)
        Op[(long long)t * 64 + nd * 16 + lo] = Oa[mi][nd][r];
    }
  }
}

// ---------------- launch ----------------
extern "C" void kernel_launch(void* const* d_in, const int* in_sizes, int n_in,
                              void* d_out, int out_size, void* d_ws, size_t ws_size,
                              hipStream_t stream) {
  const float* x  = (const float*)d_in[0];
  const float* Wk = (const float*)d_in[1];
  const float* Wq = (const float*)d_in[2];
  const float* Wv = (const float*)d_in[3];
  const float* Wp = (const float*)d_in[4];
  const float* bp = (const float*)d_in[5];
  float* out = (float*)d_out;

  char* ws = (char*)d_ws;
  __bf16* Xb  = (__bf16*)ws;                 // 4096*1024
  __bf16* Wqb = Xb  + 4194304;               // 1024*1024 each
  __bf16* Wkb = Wqb + 1048576;
  __bf16* Wvb = Wkb + 1048576;
  __bf16* Wpb = Wvb + 1048576;
  __bf16* Qh  = Wpb + 1048576;               // [B][H][T][D]
  __bf16* Kh  = Qh  + 4194304;
  __bf16* Vh  = Kh  + 4194304;
  __bf16* Yb  = Vh  + 4194304;               // (unused slot, kept for layout stability)
  float*  Opart = (float*)(Yb + 4194304);    // [2][32][2048][64] f32
  float*  lpart = Opart + 8388608;           // [2][32][2048]    f32

  cvt_bf16<<<8192, 256, 0, stream>>>(x, Wq, Wk, Wv, Wp, Xb, Wqb, Wkb, Wvb, Wpb);
  gemm_qkv<<<dim3(32, 8, 3), 256, 0, stream>>>(Xb, Wqb, Wkb, Wvb, Qh, Kh, Vh);
  attn<<<dim3(32, 8, 2), 512, 0, stream>>>(Qh, Kh, Vh, Opart, lpart);
  gemm_proj<<<dim3(64, 8), 256, 0, stream>>>(Opart, lpart, Wpb, bp, out);
}

// Round 10
// 190.016 us; speedup vs baseline: 1.0585x; 1.0031x over previous
//
#include <hip/hip_runtime.h>
#include <hip/hip_bf16.h>

// B=2, T=2048, C=1024, H=16, D=64.  M = B*T = 4096.
// out = proj( attn( x@Wq^T, x@Wk^T, x@Wv^T ) ) @ Wp^T + bp   (softmax, NO causal mask)

typedef __bf16 bf16x8 __attribute__((ext_vector_type(8)));
typedef __bf16 bf16x4 __attribute__((ext_vector_type(4)));
typedef float  f32x4  __attribute__((ext_vector_type(4)));
typedef unsigned int uint2v __attribute__((ext_vector_type(2)));

#define QSCALE 0.18033688011112042f  /* 0.125 * log2(e): softmax in exp2 domain */

__device__ __forceinline__ void gload_lds16(const void* g, void* l) {
  __builtin_amdgcn_global_load_lds((const __attribute__((address_space(1))) void*)g,
                                   (__attribute__((address_space(3))) void*)l, 16, 0, 0);
}
__device__ __forceinline__ unsigned int lds_off(const void* p) {
  return (unsigned int)(uintptr_t)(__attribute__((address_space(3))) const char*)p;
}
// ds_read_b64_tr_b16: lane l receives bf16 elems (l&15) + j*16 + (l>>4)*64 of the 512B
// region at (base&~0x1ff)+IMM when per-lane addr = base + l*8.
template<int IMM>
__device__ __forceinline__ uint2v tr_b64(unsigned int addr) {
  uint2v r;
  asm volatile("ds_read_b64_tr_b16 %0, %1 offset:%2" : "=v"(r) : "v"(addr), "i"(IMM));
  return r;
}
// packed fp32->bf16 (RNE), src0 -> low half
__device__ __forceinline__ unsigned int cvtpk_bf16(float a, float b) {
  unsigned int r;
  asm("v_cvt_pk_bf16_f32 %0, %1, %2" : "=v"(r) : "v"(a), "v"(b));
  return r;
}

// ---------------- fp32 -> bf16 conversion ----------------
__global__ __launch_bounds__(256) void cvt_bf16(
    const float* __restrict__ x,  const float* __restrict__ wq, const float* __restrict__ wk,
    const float* __restrict__ wv, const float* __restrict__ wp,
    __bf16* __restrict__ xb,  __bf16* __restrict__ wqb, __bf16* __restrict__ wkb,
    __bf16* __restrict__ wvb, __bf16* __restrict__ wpb) {
  long long i = ((long long)blockIdx.x * 256 + threadIdx.x) * 4;
  const float* src; __bf16* dst; long long off;
  if      (i < 4194304LL) { src = x;  dst = xb;  off = i; }
  else if (i < 5242880LL) { src = wq; dst = wqb; off = i - 4194304LL; }
  else if (i < 6291456LL) { src = wk; dst = wkb; off = i - 5242880LL; }
  else if (i < 7340032LL) { src = wv; dst = wvb; off = i - 6291456LL; }
  else                    { src = wp; dst = wpb; off = i - 7340032LL; }
  float4 v = *(const float4*)(src + off);
  bf16x4 o;
  o[0] = (__bf16)v.x; o[1] = (__bf16)v.y; o[2] = (__bf16)v.z; o[3] = (__bf16)v.w;
  *(bf16x4*)(dst + off) = o;
}

// ------- single-buffered GEMM core (round-4 proven): C[(MFR*32) x 128] ----------------
// LDS rows linear 128B, source pre-swizzled; reads XOR-swizzled -> conflict-free.
template<int MFR>
__device__ __forceinline__ void gemm_core_sb(
    const __bf16* __restrict__ A, const __bf16* __restrict__ Bw,
    int tileM, int tileN, char* smA, char* smB, f32x4 (&acc)[MFR][4]) {
  const int tid = threadIdx.x;
  const int lane = tid & 63;
  const int wid = tid >> 6;
  const int wr = wid >> 1, wc = wid & 1;
  #pragma unroll 1
  for (int k0 = 0; k0 < 1024; k0 += 64) {
    __syncthreads();
    #pragma unroll
    for (int r = 0; r < MFR; ++r) {
      int ci = tid + 256 * r;
      int row = ci >> 3, c = ci & 7;
      int sc = (c ^ (row & 7)) * 8;
      gload_lds16(A + (long long)(tileM + row) * 1024 + k0 + sc, smA + ci * 16);
    }
    #pragma unroll
    for (int r = 0; r < 4; ++r) {
      int ci = tid + 256 * r;
      int row = ci >> 3, c = ci & 7;
      int sc = (c ^ (row & 7)) * 8;
      gload_lds16(Bw + (long long)(tileN + row) * 1024 + k0 + sc, smB + ci * 16);
    }
    __syncthreads();
    #pragma unroll
    for (int kk = 0; kk < 2; ++kk) {
      bf16x8 af[MFR], bfr[4];
      #pragma unroll
      for (int i = 0; i < MFR; ++i) {
        int mrow = wr * (MFR * 16) + i * 16 + (lane & 15);
        af[i] = *(const bf16x8*)(smA + mrow * 128 +
                  ((kk * 64 + (lane >> 4) * 16) ^ ((mrow & 7) << 4)));
      }
      #pragma unroll
      for (int i = 0; i < 4; ++i) {
        int nrow = wc * 64 + i * 16 + (lane & 15);
        bfr[i] = *(const bf16x8*)(smB + nrow * 128 +
                  ((kk * 64 + (lane >> 4) * 16) ^ ((nrow & 7) << 4)));
      }
      __builtin_amdgcn_s_setprio(1);
      #pragma unroll
      for (int mi = 0; mi < MFR; ++mi)
        #pragma unroll
        for (int ni = 0; ni < 4; ++ni)
          acc[mi][ni] = __builtin_amdgcn_mfma_f32_16x16x32_bf16(af[mi], bfr[ni], acc[mi][ni], 0, 0, 0);
      __builtin_amdgcn_s_setprio(0);
    }
  }
}

// ---------------- QKV projection: writes [B][H][T][D] bf16, Q pre-scaled ----------------
__global__ __launch_bounds__(256) void gemm_qkv(
    const __bf16* __restrict__ Xb, const __bf16* __restrict__ Wqb,
    const __bf16* __restrict__ Wkb, const __bf16* __restrict__ Wvb,
    __bf16* __restrict__ Qh, __bf16* __restrict__ Kh, __bf16* __restrict__ Vh) {
  __shared__ __align__(16) char smA[16384];
  __shared__ __align__(16) char smB[16384];
  const int z = blockIdx.z;
  const __bf16* W = (z == 0) ? Wqb : (z == 1) ? Wkb : Wvb;
  __bf16* dst     = (z == 0) ? Qh  : (z == 1) ? Kh  : Vh;
  const float scale = (z == 0) ? QSCALE : 1.0f;
  const int tileM = blockIdx.x * 128, tileN = blockIdx.y * 128;
  f32x4 acc[4][4] = {};
  gemm_core_sb<4>(Xb, W, tileM, tileN, smA, smB, acc);
  const int lane = threadIdx.x & 63, wid = threadIdx.x >> 6;
  const int wr = wid >> 1, wc = wid & 1;
  #pragma unroll
  for (int mi = 0; mi < 4; ++mi) {
    #pragma unroll
    for (int ni = 0; ni < 4; ++ni) {
      int n = tileN + wc * 64 + ni * 16 + (lane & 15);
      int h = n >> 6, d = n & 63;
      #pragma unroll
      for (int r = 0; r < 4; ++r) {
        int m = tileM + wr * 64 + mi * 16 + (lane >> 4) * 4 + r;
        int b = m >> 11, t = m & 2047;
        dst[((b * 16 + h) * 2048 + t) * 64 + d] = (__bf16)(acc[mi][ni][r] * scale);
      }
    }
  }
}

// ---------------- output projection + bias, fp32 out (64x128 tiles) ----------------
__global__ __launch_bounds__(256) void gemm_proj(
    const __bf16* __restrict__ Yb, const __bf16* __restrict__ Wpb,
    const float* __restrict__ bias, float* __restrict__ out) {
  __shared__ __align__(16) char smA[8192];
  __shared__ __align__(16) char smB[16384];
  const int tileM = blockIdx.x * 64, tileN = blockIdx.y * 128;
  f32x4 acc[2][4] = {};
  gemm_core_sb<2>(Yb, Wpb, tileM, tileN, smA, smB, acc);
  const int lane = threadIdx.x & 63, wid = threadIdx.x >> 6;
  const int wr = wid >> 1, wc = wid & 1;
  #pragma unroll
  for (int mi = 0; mi < 2; ++mi) {
    #pragma unroll
    for (int ni = 0; ni < 4; ++ni) {
      int n = tileN + wc * 64 + ni * 16 + (lane & 15);
      float bv = bias[n];
      #pragma unroll
      for (int r = 0; r < 4; ++r) {
        int m = tileM + wr * 32 + mi * 16 + (lane >> 4) * 4 + r;
        out[(long long)m * 1024 + n] = acc[mi][ni][r] + bv;
      }
    }
  }
}

// -------- flash attention, static max, Q-split (no partials), 8 waves, 2-phase --------
// Each wave: 16 q rows x all 2048 keys.  Writes normalized bf16 Yb directly.
template<int KS>
__device__ __forceinline__ void pv_half(unsigned int trP, unsigned int trV,
                                        f32x4 (&Oa)[4], f32x4& Osum, bf16x8 ones) {
  uint2v pl, ph;
  pl = tr_b64<KS * 1024      >(trP);
  ph = tr_b64<KS * 1024 + 512>(trP);
  uint2v t0[4], t1[4];
  t0[0] = tr_b64<KS * 1024 + 0 * 2048>(trV);  t1[0] = tr_b64<KS * 1024 + 0 * 2048 + 512>(trV);
  t0[1] = tr_b64<KS * 1024 + 1 * 2048>(trV);  t1[1] = tr_b64<KS * 1024 + 1 * 2048 + 512>(trV);
  t0[2] = tr_b64<KS * 1024 + 2 * 2048>(trV);  t1[2] = tr_b64<KS * 1024 + 2 * 2048 + 512>(trV);
  t0[3] = tr_b64<KS * 1024 + 3 * 2048>(trV);  t1[3] = tr_b64<KS * 1024 + 3 * 2048 + 512>(trV);
  asm volatile("s_waitcnt lgkmcnt(0)");
  __builtin_amdgcn_sched_barrier(0);
  __builtin_amdgcn_s_setprio(1);
  uint4 up; up.x = pl[0]; up.y = pl[1]; up.z = ph[0]; up.w = ph[1];
  bf16x8 pa = __builtin_bit_cast(bf16x8, up);
  Osum = __builtin_amdgcn_mfma_f32_16x16x32_bf16(pa, ones, Osum, 0, 0, 0);
  #pragma unroll
  for (int nd = 0; nd < 4; ++nd) {
    uint4 u; u.x = t0[nd][0]; u.y = t0[nd][1]; u.z = t1[nd][0]; u.w = t1[nd][1];
    bf16x8 vf = __builtin_bit_cast(bf16x8, u);
    Oa[nd] = __builtin_amdgcn_mfma_f32_16x16x32_bf16(pa, vf, Oa[nd], 0, 0, 0);
  }
  __builtin_amdgcn_s_setprio(0);
}

__global__ __launch_bounds__(512, 6) void attn(
    const __bf16* __restrict__ Qh, const __bf16* __restrict__ Kh,
    const __bf16* __restrict__ Vh, __bf16* __restrict__ Yb) {
  __shared__ __align__(16) char Ksm[2][8192];   // [64 keys][64 d] swizzled rows, dbuf
  __shared__ __align__(16) char Vsm[2][8192];   // tr-read layout, dbuf
  __shared__ __align__(16) char Psm[16384];     // per-wave P^T, tr-read layout (8 x 2KB)
  const int tid = threadIdx.x, lane = tid & 63, wid = tid >> 6;
  const int lo = lane & 15, hi = lane >> 4;
  const int bh = blockIdx.x;                 // 0..31 = b*16+h
  const int qb = blockIdx.y;                 // 0..15
  const int base = bh * (2048 * 64);
  const int qrow0 = qb * 128 + wid * 16;     // 16 q rows per wave

  bf16x8 qf[2];
  #pragma unroll
  for (int kk = 0; kk < 2; ++kk)
    qf[kk] = *(const bf16x8*)(Qh + base + (qrow0 + lo) * 64 + kk * 32 + hi * 8);

  bf16x8 ones;
  #pragma unroll
  for (int j = 0; j < 8; ++j) ones[j] = (__bf16)1.0f;

  f32x4 Oa[4] = {};
  f32x4 Osum = {};
  const unsigned int trP = lds_off(Psm) + wid * 2048 + lane * 8;

  unsigned int koff[4];
  #pragma unroll
  for (int ni = 0; ni < 4; ++ni) {
    int row = ni * 16 + lo;
    koff[ni] = row * 128 + ((hi * 16) ^ ((row & 7) << 4));
  }
  unsigned int paddr[4];
  #pragma unroll
  for (int ni = 0; ni < 4; ++ni) {
    int kq = ni * 16 + lo;
    paddr[ni] = wid * 2048 + (kq >> 5) * 1024 + ((kq >> 2) & 1) * 512 +
                ((kq >> 3) & 3) * 128 + (kq & 3) * 32 + hi * 8;
  }

  // staging: 1 chunk of K + 1 chunk of V per thread (512 threads)
  int krow = tid >> 3, kc = tid & 7;
  int ksrc = base + krow * 64 + (kc ^ (krow & 7)) * 8;
  int kdst = tid * 16;
  int vcc = tid >> 6, vks = vcc & 1, vd4 = vcc >> 1;
  int vkey = vks * 32 + ((lane >> 3) & 3) * 8 + ((lane >> 5) & 1) * 4 + ((lane >> 1) & 3);
  int vsrc = base + vkey * 64 + vd4 * 16 + (lane & 1) * 8;
  int vdst = vks * 1024 + vd4 * 2048 + lane * 16;

  gload_lds16(Kh + ksrc, &Ksm[0][0] + kdst);
  gload_lds16(Vh + vsrc, &Vsm[0][0] + vdst);
  __syncthreads();
  int buf = 0;

  #pragma unroll 1
  for (int kt = 0; kt < 32; ++kt) {
    if (kt < 31) {
      gload_lds16(Kh + ksrc + (kt + 1) * 4096, &Ksm[buf ^ 1][0] + kdst);
      gload_lds16(Vh + vsrc + (kt + 1) * 4096, &Vsm[buf ^ 1][0] + vdst);
    }
    __builtin_amdgcn_sched_barrier(0);

    const char* Kb = &Ksm[buf][0];
    const unsigned int trV = lds_off(Vsm) + buf * 8192 + lane * 8;

    // S = Q * K^T  (16 q rows x 64 keys)
    f32x4 S[4] = {};
    #pragma unroll
    for (int kk = 0; kk < 2; ++kk) {
      bf16x8 kf[4];
      #pragma unroll
      for (int ni = 0; ni < 4; ++ni)
        kf[ni] = *(const bf16x8*)(Kb + (koff[ni] ^ (kk * 64)));
      __builtin_amdgcn_s_setprio(1);
      #pragma unroll
      for (int ni = 0; ni < 4; ++ni)
        S[ni] = __builtin_amdgcn_mfma_f32_16x16x32_bf16(qf[kk], kf[ni], S[ni], 0, 0, 0);
      __builtin_amdgcn_s_setprio(0);
    }

    // static-max softmax: p = exp2(S); packed cvt_pk -> one b64 write per ni
    #pragma unroll
    for (int ni = 0; ni < 4; ++ni) {
      float e0 = exp2f(S[ni][0]);
      float e1 = exp2f(S[ni][1]);
      float e2 = exp2f(S[ni][2]);
      float e3 = exp2f(S[ni][3]);
      uint2v w;
      w[0] = cvtpk_bf16(e0, e1);
      w[1] = cvtpk_bf16(e2, e3);
      *(uint2v*)(&Psm[0] + paddr[ni]) = w;
    }

    pv_half<0>(trP, trV, Oa, Osum, ones);
    pv_half<1>(trP, trV, Oa, Osum, ones);

    __syncthreads();
    buf ^= 1;
  }

  // epilogue: normalize and write bf16 Yb [B][T][C] directly
  const int b = bh >> 4, h = bh & 15;
  #pragma unroll
  for (int r = 0; r < 4; ++r) {
    float inv = 1.0f / Osum[r];
    int t = qrow0 + hi * 4 + r;
    #pragma unroll
    for (int nd = 0; nd < 4; ++nd)
      Yb[(b * 2048 + t) * 1024 + h * 64 + nd * 16 + lo] = (__bf16)(Oa[nd][r] * inv);
  }
}

// ---------------- launch ----------------
extern "C" void kernel_launch(void* const* d_in, const int* in_sizes, int n_in,
                              void* d_out, int out_size, void* d_ws, size_t ws_size,
                              hipStream_t stream) {
  const float* x  = (const float*)d_in[0];
  const float* Wk = (const float*)d_in[1];
  const float* Wq = (const float*)d_in[2];
  const float* Wv = (const float*)d_in[3];
  const float* Wp = (const float*)d_in[4];
  const float* bp = (const float*)d_in[5];
  float* out = (float*)d_out;

  char* ws = (char*)d_ws;
  __bf16* Xb  = (__bf16*)ws;                 // 4096*1024
  __bf16* Wqb = Xb  + 4194304;               // 1024*1024 each
  __bf16* Wkb = Wqb + 1048576;
  __bf16* Wvb = Wkb + 1048576;
  __bf16* Wpb = Wvb + 1048576;
  __bf16* Qh  = Wpb + 1048576;               // [B][H][T][D]
  __bf16* Kh  = Qh  + 4194304;
  __bf16* Vh  = Kh  + 4194304;
  __bf16* Yb  = Vh  + 4194304;               // [B][T][C] bf16

  cvt_bf16<<<8192, 256, 0, stream>>>(x, Wq, Wk, Wv, Wp, Xb, Wqb, Wkb, Wvb, Wpb);
  gemm_qkv<<<dim3(32, 8, 3), 256, 0, stream>>>(Xb, Wqb, Wkb, Wvb, Qh, Kh, Vh);
  attn<<<dim3(32, 16), 512, 0, stream>>>(Qh, Kh, Vh, Yb);
  gemm_proj<<<dim3(64, 8), 256, 0, stream>>>(Yb, Wpb, bp, out);
}